// Round 4
// baseline (556.865 us; speedup 1.0000x reference)
//
#include <hip/hip_runtime.h>
#include <hip/hip_bf16.h>

#define HS 12       // stride for h / xr rows (48B)
#define XLU 8       // stride (uints) for bf16 xl rows (32B, sector-aligned)
#define USU 12      // stride (uints) for packed bf16 u-rows (48B; 64B stride regressed: cache footprint > line-split win)
#define NPART 8     // p-histogram partitions
#define N_CAP 200000
#define M_CAP 32768
#define E_CAP 3200000
#define BKS 10      // 1024 nodes per bucket (196 buckets)
#define CHUNK 6144  // edges per k_bscatter block

// Static device scratch
__device__ __align__(32) unsigned g_xlbA[(size_t)N_CAP * XLU];
__device__ __align__(32) unsigned g_xlbB[(size_t)N_CAP * XLU];
__device__ __align__(16) float    g_xrA[(size_t)N_CAP * HS];
__device__ __align__(16) float    g_xrB[(size_t)N_CAP * HS];
__device__ __align__(16) float    g_h [(size_t)N_CAP * HS];
__device__ __align__(16) unsigned g_us[(size_t)N_CAP * USU];
__device__ __align__(16) unsigned g_ud[(size_t)N_CAP * USU];
__device__ __align__(16) unsigned g_ut[(size_t)N_CAP * USU];
__device__ int      g_cnt[N_CAP];
__device__ int      g_off[N_CAP];
__device__ int      g_bcnt[256];
__device__ int      g_boff[256];
__device__ int      g_bcur[256];
__device__ unsigned g_staged[E_CAP];
__device__ int      g_csrc[E_CAP];
__device__ __align__(64) float g_pp[NPART][M_CAP];
__device__ float    g_p[M_CAP];
__device__ float    g_vsum[1];
__device__ float    g_bmax[M_CAP / 256];
__device__ float    g_bsum[M_CAP / 256];
__device__ float    g_lse[1];

__device__ __forceinline__ unsigned* xlb_buf(int s) { return s ? g_xlbB : g_xlbA; }
__device__ __forceinline__ float*    xr_buf(int s)  { return s ? g_xrB : g_xrA; }

__device__ __forceinline__ void load_row10(const float* row, float* v) {
    const float4* r4 = (const float4*)row;
    float4 a = r4[0], b = r4[1];
    float2 c = ((const float2*)row)[4];
    v[0] = a.x; v[1] = a.y; v[2] = a.z; v[3] = a.w;
    v[4] = b.x; v[5] = b.y; v[6] = b.z; v[7] = b.w;
    v[8] = c.x; v[9] = c.y;
}
__device__ __forceinline__ unsigned pack_bf2(float a, float b) {
    unsigned ua = __float_as_uint(a); ua = (ua + 0x7fffu + ((ua >> 16) & 1u)) >> 16;
    unsigned ub = __float_as_uint(b); ub = (ub + 0x7fffu + ((ub >> 16) & 1u)) >> 16;
    return ua | (ub << 16);
}
__device__ __forceinline__ void unpack_bf2(unsigned u, float& a, float& b) {
    a = __uint_as_float(u << 16);
    b = __uint_as_float(u & 0xffff0000u);
}
__device__ __forceinline__ void load_xlb(const unsigned* row, float* v) {
    uint4 q = ((const uint4*)row)[0];
    unsigned q4 = row[4];
    unpack_bf2(q.x, v[0], v[1]); unpack_bf2(q.y, v[2], v[3]);
    unpack_bf2(q.z, v[4], v[5]); unpack_bf2(q.w, v[6], v[7]);
    unpack_bf2(q4, v[8], v[9]);
}
__device__ __forceinline__ void store_xlb(unsigned* row, const float* v) {
    ((uint4*)row)[0] = make_uint4(pack_bf2(v[0], v[1]), pack_bf2(v[2], v[3]),
                                  pack_bf2(v[4], v[5]), pack_bf2(v[6], v[7]));
    row[4] = pack_bf2(v[8], v[9]);
}
__device__ __forceinline__ void load_row20_pk(const unsigned* row, unsigned* w) {
    uint4 t0 = ((const uint4*)row)[0];
    uint4 t1 = ((const uint4*)row)[1];
    uint2 t2 = ((const uint2*)row)[4];
    w[0] = t0.x; w[1] = t0.y; w[2] = t0.z; w[3] = t0.w;
    w[4] = t1.x; w[5] = t1.y; w[6] = t1.z; w[7] = t1.w;
    w[8] = t2.x; w[9] = t2.y;
}
__device__ __forceinline__ void store_row20_bf(unsigned* row, const float* v) {
    uint4* r4 = (uint4*)row;
    r4[0] = make_uint4(pack_bf2(v[0], v[1]), pack_bf2(v[2], v[3]),
                       pack_bf2(v[4], v[5]), pack_bf2(v[6], v[7]));
    r4[1] = make_uint4(pack_bf2(v[8], v[9]), pack_bf2(v[10], v[11]),
                       pack_bf2(v[12], v[13]), pack_bf2(v[14], v[15]));
    r4[2] = make_uint4(pack_bf2(v[16], v[17]), pack_bf2(v[18], v[19]), 0u, 0u);
}

// ---- one edge's contribution (no-max softmax: logits bounded ~|e|<15 << 88,
// so raw expf cannot overflow; removes divergent rescale + max merges) ----
__device__ __forceinline__ void edge_accum(uint4 qa, unsigned qb, float valid,
                                           const float* xr, const float* satt,
                                           float* num, float& den) {
    float xls[10];
    unpack_bf2(qa.x, xls[0], xls[1]); unpack_bf2(qa.y, xls[2], xls[3]);
    unpack_bf2(qa.z, xls[4], xls[5]); unpack_bf2(qa.w, xls[6], xls[7]);
    unpack_bf2(qb, xls[8], xls[9]);
    float acc = 0.f;
#pragma unroll
    for (int k = 0; k < 10; k++) {
        float v = xls[k] + xr[k];
        v = (v > 0.f) ? v : 0.2f * v;
        acc += v * satt[k];
    }
    float w = valid * __expf(acc);
    den += w;
#pragma unroll
    for (int j = 0; j < 10; j++) num[j] += w * xls[j];
}

// ---- shared gather core (batch-4 loads: all 4 indices, then all 4 rows in
// flight together -> one latency exposure per ~4 edges instead of per edge) ----
__device__ __forceinline__ void gather_core(int n, int sub, const unsigned* xlb,
                                            const float* xr_arr, const float* satt,
                                            const float* sb, float* hout) {
    float xr[10];
    load_row10(&xr_arr[(size_t)n * HS], xr);
    float den = 0.f, num[10];
#pragma unroll
    for (int j = 0; j < 10; j++) num[j] = 0.f;
    if (sub == 0) {   // self-loop
        const unsigned* rp = &xlb[(size_t)n * XLU];
        uint4 qa = ((const uint4*)rp)[0];
        unsigned qb = rp[4];
        edge_accum(qa, qb, 1.f, xr, satt, num, den);
    }
    int lo = g_off[n], hi = lo + g_cnt[n];
    for (int e = lo + sub; e < hi; e += 16) {
        int r = hi - e;
        // 4 independent index loads (0 for tail: row-0 read, weight 0)
        int s0 = g_csrc[e];
        int s1 = (r > 4)  ? g_csrc[e + 4]  : 0;
        int s2 = (r > 8)  ? g_csrc[e + 8]  : 0;
        int s3 = (r > 12) ? g_csrc[e + 12] : 0;
        // 4 independent row loads
        const unsigned* r0 = &xlb[(size_t)s0 * XLU];
        const unsigned* r1 = &xlb[(size_t)s1 * XLU];
        const unsigned* r2 = &xlb[(size_t)s2 * XLU];
        const unsigned* r3 = &xlb[(size_t)s3 * XLU];
        uint4 qa0 = ((const uint4*)r0)[0]; unsigned qb0 = r0[4];
        uint4 qa1 = ((const uint4*)r1)[0]; unsigned qb1 = r1[4];
        uint4 qa2 = ((const uint4*)r2)[0]; unsigned qb2 = r2[4];
        uint4 qa3 = ((const uint4*)r3)[0]; unsigned qb3 = r3[4];
        edge_accum(qa0, qb0, 1.f, xr, satt, num, den);
        edge_accum(qa1, qb1, (r > 4)  ? 1.f : 0.f, xr, satt, num, den);
        edge_accum(qa2, qb2, (r > 8)  ? 1.f : 0.f, xr, satt, num, den);
        edge_accum(qa3, qb3, (r > 12) ? 1.f : 0.f, xr, satt, num, den);
    }
#pragma unroll
    for (int off = 1; off <= 2; off <<= 1) {
        den += __shfl_xor(den, off);
#pragma unroll
        for (int j = 0; j < 10; j++) num[j] += __shfl_xor(num[j], off);
    }
    float inv = 1.f / den;
#pragma unroll
    for (int j = 0; j < 10; j++) {
        float v = num[j] * inv + sb[j];
        hout[j] = (v > 0.f) ? v : 0.f;
    }
}

// ---------------- init ----------------
__global__ void k_init(int M) {
    int i = blockIdx.x * blockDim.x + threadIdx.x;
    int tot = NPART * M;
    if (i < tot) ((float*)g_pp)[i] = 0.f;
    if (i < 256) g_bcnt[i] = 0;
    if (i == tot) g_vsum[0] = 0.f;
}

// ---------------- CSR build ----------------
__global__ void k_bhist(const int* __restrict__ dst, int E) {
    __shared__ int hist[256];
    hist[threadIdx.x] = 0;
    __syncthreads();
    for (int e = blockIdx.x * blockDim.x + threadIdx.x; e < E; e += gridDim.x * blockDim.x)
        atomicAdd(&hist[dst[e] >> BKS], 1);
    __syncthreads();
    int v = hist[threadIdx.x];
    if (v) atomicAdd(&g_bcnt[threadIdx.x], v);
}
__global__ void k_bscan() {
    __shared__ int s[256];
    int t = threadIdx.x;
    int v = g_bcnt[t];
    s[t] = v;
    __syncthreads();
    for (int d = 1; d < 256; d <<= 1) {
        int x = (t >= d) ? s[t - d] : 0;
        __syncthreads();
        s[t] += x;
        __syncthreads();
    }
    g_boff[t] = s[t] - v;
    g_bcur[t] = s[t] - v;
}
__global__ void k_bscatter(const int* __restrict__ src, const int* __restrict__ dst, int E) {
    __shared__ int hist[256], cur[256];
    int lo = blockIdx.x * CHUNK;
    int hi = lo + CHUNK; if (hi > E) hi = E;
    int tid = threadIdx.x;
    hist[tid] = 0;
    __syncthreads();
    for (int e = lo + tid; e < hi; e += 256) atomicAdd(&hist[dst[e] >> BKS], 1);
    __syncthreads();
    int h = hist[tid];
    cur[tid] = h ? atomicAdd(&g_bcur[tid], h) : 0;
    __syncthreads();
    for (int e = lo + tid; e < hi; e += 256) {
        int d = dst[e];
        int pos = atomicAdd(&cur[d >> BKS], 1);
        g_staged[pos] = ((unsigned)src[e] << BKS) | (unsigned)(d & ((1 << BKS) - 1));
    }
}
__global__ void k_bgroup(int N, int E, int nbk) {
    __shared__ int cnt[1024], offl[1024], ssum[512];
    int b = blockIdx.x;
    int nodebase = b << BKS;
    int bstart = g_boff[b];
    int bend = (b + 1 < nbk) ? g_boff[b + 1] : E;
    int tid = threadIdx.x;
    cnt[tid] = 0; cnt[tid + 512] = 0;
    __syncthreads();
    for (int e = bstart + tid; e < bend; e += 512)
        atomicAdd(&cnt[g_staged[e] & 1023u], 1);
    __syncthreads();
    int s0 = cnt[2 * tid], s1 = cnt[2 * tid + 1];
    int tsum = s0 + s1;
    ssum[tid] = tsum;
    __syncthreads();
    for (int d = 1; d < 512; d <<= 1) {
        int x = (tid >= d) ? ssum[tid - d] : 0;
        __syncthreads();
        ssum[tid] += x;
        __syncthreads();
    }
    int base = ssum[tid] - tsum;
    offl[2 * tid] = base;
    offl[2 * tid + 1] = base + s0;
    __syncthreads();
    int n0 = nodebase + 2 * tid, n1 = n0 + 1;
    if (n0 < N) { g_off[n0] = bstart + offl[2 * tid]; g_cnt[n0] = s0; }
    if (n1 < N) { g_off[n1] = bstart + offl[2 * tid + 1]; g_cnt[n1] = s1; }
    cnt[2 * tid] = offl[2 * tid];
    cnt[2 * tid + 1] = offl[2 * tid + 1];
    __syncthreads();
    for (int e = bstart + tid; e < bend; e += 512) {
        unsigned w = g_staged[e];
        int p = atomicAdd(&cnt[w & 1023u], 1);
        g_csrc[bstart + p] = (int)(w >> BKS);
    }
}

// ---- layer-1 pre ----
__global__ void k_pre1(const float* __restrict__ x1,
                       const float* __restrict__ wl, const float* __restrict__ wr, int N) {
    __shared__ float swl[150], swr[150];
    for (int t = threadIdx.x; t < 150; t += blockDim.x) { swl[t] = wl[t]; swr[t] = wr[t]; }
    __syncthreads();
    int n = blockIdx.x * blockDim.x + threadIdx.x;
    if (n >= N) return;
    float aL[10], aR[10];
#pragma unroll
    for (int j = 0; j < 10; j++) { aL[j] = 0.f; aR[j] = 0.f; }
    for (int k = 0; k < 15; k++) {
        float v = x1[(size_t)n * 15 + k];
#pragma unroll
        for (int j = 0; j < 10; j++) { aL[j] += v * swl[k * 10 + j]; aR[j] += v * swr[k * 10 + j]; }
    }
    store_xlb(&g_xlbA[(size_t)n * XLU], aL);
#pragma unroll
    for (int j = 0; j < 10; j++) g_xrA[(size_t)n * HS + j] = aR[j];
}

// ---- fused gather(L) + pre(L+1) ----
__global__ void k_gather_pre(const float* __restrict__ x1,
                             const float* __restrict__ att, const float* __restrict__ b,
                             const float* __restrict__ wl, const float* __restrict__ wr,
                             int sel_in, int N) {
    __shared__ float satt[10], sb[10], swl[250], swr[250];
    if (threadIdx.x < 10) { satt[threadIdx.x] = att[threadIdx.x]; sb[threadIdx.x] = b[threadIdx.x]; }
    for (int t = threadIdx.x; t < 250; t += blockDim.x) { swl[t] = wl[t]; swr[t] = wr[t]; }
    __syncthreads();
    int t = blockIdx.x * blockDim.x + threadIdx.x;
    int n = t >> 2, sub = t & 3;
    if (n >= N) return;
    const unsigned* xlb = xlb_buf(sel_in);
    const float* xr_arr = xr_buf(sel_in);
    unsigned* xlb_o = xlb_buf(1 - sel_in);
    float* xr_o = xr_buf(1 - sel_in);
    float h[10];
    gather_core(n, sub, xlb, xr_arr, satt, sb, h);
    if (sub == 0) {
        float aL[10], aR[10];
#pragma unroll
        for (int j = 0; j < 10; j++) { aL[j] = 0.f; aR[j] = 0.f; }
        for (int k = 0; k < 10; k++) {
            float v = h[k];
#pragma unroll
            for (int j = 0; j < 10; j++) { aL[j] += v * swl[k * 10 + j]; aR[j] += v * swr[k * 10 + j]; }
        }
        for (int k = 0; k < 15; k++) {
            float v = x1[(size_t)n * 15 + k];
#pragma unroll
            for (int j = 0; j < 10; j++) { aL[j] += v * swl[(10 + k) * 10 + j]; aR[j] += v * swr[(10 + k) * 10 + j]; }
        }
        store_xlb(&xlb_o[(size_t)n * XLU], aL);
#pragma unroll
        for (int j = 0; j < 10; j++) xr_o[(size_t)n * HS + j] = aR[j];
    }
}

// ---- final gather (layer 3): writes h ----
__global__ void k_gather3(const float* __restrict__ att, const float* __restrict__ b,
                          int sel_in, int N) {
    __shared__ float satt[10], sb[10];
    if (threadIdx.x < 10) { satt[threadIdx.x] = att[threadIdx.x]; sb[threadIdx.x] = b[threadIdx.x]; }
    __syncthreads();
    int t = blockIdx.x * blockDim.x + threadIdx.x;
    int n = t >> 2, sub = t & 3;
    if (n >= N) return;
    float h[10];
    gather_core(n, sub, xlb_buf(sel_in), xr_buf(sel_in), satt, sb, h);
    if (sub == 0) {
#pragma unroll
        for (int j = 0; j < 10; j++) g_h[(size_t)n * HS + j] = h[j];
    }
}

// ---- fused: pre-project u-rows (bf16) + value head partial sum ----
// __launch_bounds__(256,1): ~110 live floats/thread -> needs >=128 VGPRs.
// Default cap (64 VGPR) caused scratch spilling: WRITE_SIZE 155MB vs 29MB payload.
__global__ void __launch_bounds__(256, 1)
k_prep_value(const float* __restrict__ x1,
             const float* __restrict__ aw, const float* __restrict__ cw,
             const float* __restrict__ x2,
             const float* __restrict__ w1, const float* __restrict__ b1,
             const float* __restrict__ w2, const float* __restrict__ bias2,
             int N) {
    __shared__ float sA[48 * 20], sC[23 * 20], sw1[29 * 15];
    __shared__ float sb1[15], sw2v[15], sx2[4], sb2v;
    __shared__ float red[256];
    for (int t = threadIdx.x; t < 48 * 20; t += blockDim.x) sA[t] = aw[t];
    for (int t = threadIdx.x; t < 23 * 20; t += blockDim.x) sC[t] = cw[t];
    for (int t = threadIdx.x; t < 29 * 15; t += blockDim.x) sw1[t] = w1[t];
    if (threadIdx.x < 15) { sb1[threadIdx.x] = b1[threadIdx.x]; sw2v[threadIdx.x] = w2[threadIdx.x]; }
    if (threadIdx.x < 4) sx2[threadIdx.x] = x2[threadIdx.x];
    if (threadIdx.x == 0) sb2v = bias2[0];
    __syncthreads();
    int n = blockIdx.x * blockDim.x + threadIdx.x;
    float vout = 0.f;
    if (n < N) {
        float hv[10], xv[15];
        load_row10(&g_h[(size_t)n * HS], hv);
#pragma unroll
        for (int k = 0; k < 15; k++) xv[k] = x1[(size_t)n * 15 + k];
        float us[20], ud[20], ut[20];
#pragma unroll
        for (int j = 0; j < 20; j++) { us[j] = 0.f; ud[j] = 0.f; ut[j] = 0.f; }
        for (int k = 0; k < 10; k++) {
            float h = hv[k];
#pragma unroll
            for (int j = 0; j < 20; j++) {
                us[j] += h * sA[k * 20 + j];
                ud[j] += h * sA[(10 + k) * 20 + j];
                ut[j] += h * sC[k * 20 + j];
            }
        }
        for (int k = 0; k < 12; k++) {
            float v = xv[3 + k];
#pragma unroll
            for (int j = 0; j < 20; j++) {
                us[j] += v * sA[(20 + k) * 20 + j];
                ut[j] += v * sC[(10 + k) * 20 + j];
            }
        }
        for (int k = 0; k < 14; k++) {
            float v = xv[1 + k];
#pragma unroll
            for (int j = 0; j < 20; j++) ud[j] += v * sA[(32 + k) * 20 + j];
        }
        float t34 = -0.7f * (xv[3] + xv[4]);
#pragma unroll
        for (int j = 0; j < 20; j++) ud[j] += t34 * sA[47 * 20 + j];
        store_row20_bf(&g_us[(size_t)n * USU], us);
        store_row20_bf(&g_ud[(size_t)n * USU], ud);
        store_row20_bf(&g_ut[(size_t)n * USU], ut);
        float acc[15];
#pragma unroll
        for (int j = 0; j < 15; j++) acc[j] = sb1[j];
        for (int k = 0; k < 10; k++) {
            float f = hv[k];
#pragma unroll
            for (int j = 0; j < 15; j++) acc[j] += f * sw1[k * 15 + j];
        }
        for (int k = 0; k < 15; k++) {
            float f = xv[k];
#pragma unroll
            for (int j = 0; j < 15; j++) acc[j] += f * sw1[(10 + k) * 15 + j];
        }
        for (int k = 0; k < 4; k++) {
            float f = sx2[k];
#pragma unroll
            for (int j = 0; j < 15; j++) acc[j] += f * sw1[(25 + k) * 15 + j];
        }
        vout = sb2v;
#pragma unroll
        for (int j = 0; j < 15; j++) { float r = (acc[j] > 0.f) ? acc[j] : 0.f; vout += r * sw2v[j]; }
    }
    red[threadIdx.x] = vout;
    __syncthreads();
    for (int s = 128; s > 0; s >>= 1) {
        if (threadIdx.x < (unsigned)s) red[threadIdx.x] += red[threadIdx.x + s];
        __syncthreads();
    }
    if (threadIdx.x == 0) atomicAdd(&g_vsum[0], red[0]);
}

// ---- fused attack + deploy scoring; 2 items/thread for double MLP ----
__global__ void k_score(const int* __restrict__ asrc, const int* __restrict__ adst,
                        const float* __restrict__ aarm, const int* __restrict__ amove,
                        const float* __restrict__ aw, const float* __restrict__ ab,
                        const float* __restrict__ bw, const float* __restrict__ bb,
                        const int* __restrict__ dtar, const float* __restrict__ darm,
                        const int* __restrict__ dmove,
                        const float* __restrict__ cw, const float* __restrict__ cb,
                        const float* __restrict__ dw, const float* __restrict__ db,
                        int Ma, int Md, int na) {
    __shared__ float swa[20], sbias[20], sw2[20], sb2s;
    bool isA = (blockIdx.x < (unsigned)na);
    float* pp = g_pp[blockIdx.x & (NPART - 1)];
    if (threadIdx.x < 20) {
        if (isA) {
            swa[threadIdx.x] = aw[46 * 20 + threadIdx.x] + 0.6f * aw[47 * 20 + threadIdx.x];
            sbias[threadIdx.x] = ab[threadIdx.x];
            sw2[threadIdx.x] = bw[threadIdx.x];
        } else {
            swa[threadIdx.x] = cw[22 * 20 + threadIdx.x];
            sbias[threadIdx.x] = cb[threadIdx.x];
            sw2[threadIdx.x] = dw[threadIdx.x];
        }
    }
    if (threadIdx.x == 0) sb2s = isA ? bb[0] : db[0];
    __syncthreads();
    float sb2 = sb2s;
    if (isA) {
        int half = (Ma + 1) >> 1;
        int i1 = blockIdx.x * blockDim.x + threadIdx.x;
        if (i1 >= half) return;
        int i2 = i1 + half;
        bool v2 = i2 < Ma;
        int i2c = v2 ? i2 : i1;
        // all stream loads up front
        int s1 = asrc[i1], d1 = adst[i1];
        int s2 = asrc[i2c], d2 = adst[i2c];
        float a1 = aarm[i1], a2 = aarm[i2c];
        int m1 = amove[i1], m2 = amove[i2c];
        // 4 independent row gathers (12 loads in flight)
        unsigned u1[10], v1[10], u2[10], w2r[10];
        load_row20_pk(&g_us[(size_t)s1 * USU], u1);
        load_row20_pk(&g_ud[(size_t)d1 * USU], v1);
        load_row20_pk(&g_us[(size_t)s2 * USU], u2);
        load_row20_pk(&g_ud[(size_t)d2 * USU], w2r);
        float sr1 = sb2, sr2 = sb2;
#pragma unroll
        for (int q = 0; q < 10; q++) {
            float ua, ub, da, db_;
            unpack_bf2(u1[q], ua, ub); unpack_bf2(v1[q], da, db_);
            float acc0 = sbias[2 * q] + ua + da + a1 * swa[2 * q];
            float acc1 = sbias[2 * q + 1] + ub + db_ + a1 * swa[2 * q + 1];
            sr1 += ((acc0 > 0.f) ? acc0 : 0.f) * sw2[2 * q]
                 + ((acc1 > 0.f) ? acc1 : 0.f) * sw2[2 * q + 1];
        }
#pragma unroll
        for (int q = 0; q < 10; q++) {
            float ua, ub, da, db_;
            unpack_bf2(u2[q], ua, ub); unpack_bf2(w2r[q], da, db_);
            float acc0 = sbias[2 * q] + ua + da + a2 * swa[2 * q];
            float acc1 = sbias[2 * q + 1] + ub + db_ + a2 * swa[2 * q + 1];
            sr2 += ((acc0 > 0.f) ? acc0 : 0.f) * sw2[2 * q]
                 + ((acc1 > 0.f) ? acc1 : 0.f) * sw2[2 * q + 1];
        }
        atomicAdd(&pp[m1], sr1);
        if (v2) atomicAdd(&pp[m2], sr2);
    } else {
        int half = (Md + 1) >> 1;
        int i1 = (blockIdx.x - na) * blockDim.x + threadIdx.x;
        if (i1 >= half) return;
        int i2 = i1 + half;
        bool v2 = i2 < Md;
        int i2c = v2 ? i2 : i1;
        int t1 = dtar[i1], t2 = dtar[i2c];
        float a1 = darm[i1], a2 = darm[i2c];
        int m1 = dmove[i1], m2 = dmove[i2c];
        unsigned u1[10], u2[10];
        load_row20_pk(&g_ut[(size_t)t1 * USU], u1);
        load_row20_pk(&g_ut[(size_t)t2 * USU], u2);
        float sr1 = sb2, sr2 = sb2;
#pragma unroll
        for (int q = 0; q < 10; q++) {
            float ua, ub;
            unpack_bf2(u1[q], ua, ub);
            float acc0 = sbias[2 * q] + ua + a1 * swa[2 * q];
            float acc1 = sbias[2 * q + 1] + ub + a1 * swa[2 * q + 1];
            sr1 += ((acc0 > 0.f) ? acc0 : 0.f) * sw2[2 * q]
                 + ((acc1 > 0.f) ? acc1 : 0.f) * sw2[2 * q + 1];
        }
#pragma unroll
        for (int q = 0; q < 10; q++) {
            float ua, ub;
            unpack_bf2(u2[q], ua, ub);
            float acc0 = sbias[2 * q] + ua + a2 * swa[2 * q];
            float acc1 = sbias[2 * q + 1] + ub + a2 * swa[2 * q + 1];
            sr2 += ((acc0 > 0.f) ? acc0 : 0.f) * sw2[2 * q]
                 + ((acc1 > 0.f) ? acc1 : 0.f) * sw2[2 * q + 1];
        }
        atomicAdd(&pp[m1], sr1);
        if (v2) atomicAdd(&pp[m2], sr2);
    }
}

// -------- finalize (parallel): reduce partials + per-block online-softmax stats --------
__global__ void k_reduce(int M) {
    __shared__ float red[256];
    int i = blockIdx.x * 256 + threadIdx.x;
    float s = -1e30f;
    if (i < M) {
        float t = 0.f;
#pragma unroll
        for (int q = 0; q < NPART; q++) t += g_pp[q][i];
        g_p[i] = t;
        s = t;
    }
    red[threadIdx.x] = s;
    __syncthreads();
    for (int d = 128; d > 0; d >>= 1) {
        if (threadIdx.x < d) red[threadIdx.x] = fmaxf(red[threadIdx.x], red[threadIdx.x + d]);
        __syncthreads();
    }
    float bmax = red[0];
    __syncthreads();
    red[threadIdx.x] = (i < M) ? __expf(s - bmax) : 0.f;
    __syncthreads();
    for (int d = 128; d > 0; d >>= 1) {
        if (threadIdx.x < d) red[threadIdx.x] += red[threadIdx.x + d];
        __syncthreads();
    }
    if (threadIdx.x == 0) { g_bmax[blockIdx.x] = bmax; g_bsum[blockIdx.x] = red[0]; }
}

__global__ void k_lse(float* __restrict__ out, int N, int nrb) {
    __shared__ float rm[256], rs[256];
    int tid = threadIdx.x;
    float mx = -1e30f;
    for (int i = tid; i < nrb; i += 256) mx = fmaxf(mx, g_bmax[i]);
    rm[tid] = mx;
    __syncthreads();
    for (int d = 128; d > 0; d >>= 1) {
        if (tid < d) rm[tid] = fmaxf(rm[tid], rm[tid + d]);
        __syncthreads();
    }
    float pmax = rm[0];
    __syncthreads();
    float sm = 0.f;
    for (int i = tid; i < nrb; i += 256) sm += g_bsum[i] * __expf(g_bmax[i] - pmax);
    rs[tid] = sm;
    __syncthreads();
    for (int d = 128; d > 0; d >>= 1) {
        if (tid < d) rs[tid] += rs[tid + d];
        __syncthreads();
    }
    if (tid == 0) {
        g_lse[0] = pmax + logf(rs[0]);
        out[0] = tanhf(g_vsum[0] / (float)N);
    }
}

__global__ void k_write(float* __restrict__ out, int M) {
    int i = blockIdx.x * 256 + threadIdx.x;
    if (i < M) out[1 + i] = g_p[i] - g_lse[0];
}

extern "C" void kernel_launch(void* const* d_in, const int* in_sizes, int n_in,
                              void* d_out, int out_size, void* d_ws, size_t ws_size,
                              hipStream_t stream) {
    const float* x1 = (const float*)d_in[0];
    const float* x2 = (const float*)d_in[1];
    const int* edges = (const int*)d_in[2];
    const int* asrc = (const int*)d_in[3];
    const int* adst = (const int*)d_in[4];
    const float* aarm = (const float*)d_in[5];
    const int* amove = (const int*)d_in[6];
    const int* dtar = (const int*)d_in[7];
    const float* darm = (const float*)d_in[8];
    const int* dmove = (const int*)d_in[9];
    const int pb = n_in - 24;
    const float* g1_wl  = (const float*)d_in[pb + 0];
    const float* g1_wr  = (const float*)d_in[pb + 1];
    const float* g1_att = (const float*)d_in[pb + 2];
    const float* g1_b   = (const float*)d_in[pb + 3];
    const float* g2_wl  = (const float*)d_in[pb + 4];
    const float* g2_wr  = (const float*)d_in[pb + 5];
    const float* g2_att = (const float*)d_in[pb + 6];
    const float* g2_b   = (const float*)d_in[pb + 7];
    const float* g3_wl  = (const float*)d_in[pb + 8];
    const float* g3_wr  = (const float*)d_in[pb + 9];
    const float* g3_att = (const float*)d_in[pb + 10];
    const float* g3_b   = (const float*)d_in[pb + 11];
    const float* lin_w  = (const float*)d_in[pb + 12];
    const float* lin_b  = (const float*)d_in[pb + 13];
    const float* lin2_w = (const float*)d_in[pb + 14];
    const float* lin2_b = (const float*)d_in[pb + 15];
    const float* aaa_w  = (const float*)d_in[pb + 16];
    const float* aaa_b  = (const float*)d_in[pb + 17];
    const float* bbb_w  = (const float*)d_in[pb + 18];
    const float* bbb_b  = (const float*)d_in[pb + 19];
    const float* ccc_w  = (const float*)d_in[pb + 20];
    const float* ccc_b  = (const float*)d_in[pb + 21];
    const float* ddd_w  = (const float*)d_in[pb + 22];
    const float* ddd_b  = (const float*)d_in[pb + 23];

    int N = in_sizes[0] / 15;
    int E = in_sizes[2] / 2;
    const int Ma = in_sizes[3];
    const int Md = in_sizes[7];
    int M = out_size - 1;
    if (N > N_CAP) N = N_CAP;
    if (E > E_CAP) E = E_CAP;
    if (M > M_CAP) M = M_CAP;
    const int* src = edges;
    const int* dst = edges + E;

    const int nb = (N + 255) / 256;
    const int nb4 = (4 * N + 255) / 256;
    const int nbk = (N + (1 << BKS) - 1) >> BKS;
    const int nsc = (E + CHUNK - 1) / CHUNK;
    const int haM = (Ma + 1) >> 1, haD = (Md + 1) >> 1;
    const int na = (haM + 255) / 256, nd = (haD + 255) / 256;
    const int nrb = (M + 255) / 256;

    // init + CSR build (once; reused by all 3 layers)
    k_init<<<(NPART * M + 256) / 256, 256, 0, stream>>>(M);
    k_bhist<<<512, 256, 0, stream>>>(dst, E);
    k_bscan<<<1, 256, 0, stream>>>();
    k_bscatter<<<nsc, 256, 0, stream>>>(src, dst, E);
    k_bgroup<<<nbk, 512, 0, stream>>>(N, E, nbk);

    // GAT layers: pre1 -> A; gather1+pre2 -> B; gather2+pre3 -> A; gather3 -> h
    k_pre1<<<nb, 256, 0, stream>>>(x1, g1_wl, g1_wr, N);
    k_gather_pre<<<nb4, 256, 0, stream>>>(x1, g1_att, g1_b, g2_wl, g2_wr, 0, N);
    k_gather_pre<<<nb4, 256, 0, stream>>>(x1, g2_att, g2_b, g3_wl, g3_wr, 1, N);
    k_gather3<<<nb4, 256, 0, stream>>>(g3_att, g3_b, 0, N);

    // u-row projection + value head, fused attack+deploy scoring, finalize
    k_prep_value<<<nb, 256, 0, stream>>>(x1, aaa_w, ccc_w, x2, lin_w, lin_b, lin2_w, lin2_b, N);
    k_score<<<na + nd, 256, 0, stream>>>(asrc, adst, aarm, amove, aaa_w, aaa_b, bbb_w, bbb_b,
                                         dtar, darm, dmove, ccc_w, ccc_b, ddd_w, ddd_b,
                                         Ma, Md, na);
    k_reduce<<<nrb, 256, 0, stream>>>(M);
    k_lse<<<1, 256, 0, stream>>>((float*)d_out, N, nrb);
    k_write<<<nrb, 256, 0, stream>>>((float*)d_out, M);
}

// Round 5
// 539.399 us; speedup vs baseline: 1.0324x; 1.0324x over previous
//
#include <hip/hip_runtime.h>
#include <hip/hip_bf16.h>

#define HS 12       // stride for h / xr rows (48B)
#define XLU 8       // stride (uints) for bf16 xl rows (32B, sector-aligned)
#define USU 12      // stride (uints) for packed bf16 u-rows (48B; 64B stride regressed: cache footprint > line-split win)
#define NPART 8     // p-histogram partitions
#define N_CAP 200000
#define M_CAP 32768
#define E_CAP 3200000
#define BKS 10      // 1024 nodes per bucket (196 buckets)
#define CHUNK 6144  // edges per k_bscatter block

// Static device scratch
__device__ __align__(32) unsigned g_xlbA[(size_t)N_CAP * XLU];
__device__ __align__(32) unsigned g_xlbB[(size_t)N_CAP * XLU];
__device__ __align__(16) float    g_xrA[(size_t)N_CAP * HS];
__device__ __align__(16) float    g_xrB[(size_t)N_CAP * HS];
__device__ __align__(16) float    g_h [(size_t)N_CAP * HS];
__device__ __align__(16) unsigned g_us[(size_t)N_CAP * USU];
__device__ __align__(16) unsigned g_ud[(size_t)N_CAP * USU];
__device__ __align__(16) unsigned g_ut[(size_t)N_CAP * USU];
__device__ int      g_cnt[N_CAP];
__device__ int      g_off[N_CAP];
__device__ int      g_bcnt[256];
__device__ int      g_boff[256];
__device__ int      g_bcur[256];
__device__ unsigned g_staged[E_CAP];
__device__ int      g_csrc[E_CAP];
__device__ __align__(64) float g_pp[NPART][M_CAP];
__device__ float    g_p[M_CAP];
__device__ float    g_vsum[1];
__device__ float    g_bmax[M_CAP / 256];
__device__ float    g_bsum[M_CAP / 256];
__device__ float    g_lse[1];

__device__ __forceinline__ unsigned* xlb_buf(int s) { return s ? g_xlbB : g_xlbA; }
__device__ __forceinline__ float*    xr_buf(int s)  { return s ? g_xrB : g_xrA; }

__device__ __forceinline__ void load_row10(const float* row, float* v) {
    const float4* r4 = (const float4*)row;
    float4 a = r4[0], b = r4[1];
    float2 c = ((const float2*)row)[4];
    v[0] = a.x; v[1] = a.y; v[2] = a.z; v[3] = a.w;
    v[4] = b.x; v[5] = b.y; v[6] = b.z; v[7] = b.w;
    v[8] = c.x; v[9] = c.y;
}
__device__ __forceinline__ unsigned pack_bf2(float a, float b) {
    unsigned ua = __float_as_uint(a); ua = (ua + 0x7fffu + ((ua >> 16) & 1u)) >> 16;
    unsigned ub = __float_as_uint(b); ub = (ub + 0x7fffu + ((ub >> 16) & 1u)) >> 16;
    return ua | (ub << 16);
}
__device__ __forceinline__ void unpack_bf2(unsigned u, float& a, float& b) {
    a = __uint_as_float(u << 16);
    b = __uint_as_float(u & 0xffff0000u);
}
__device__ __forceinline__ void load_xlb(const unsigned* row, float* v) {
    uint4 q = ((const uint4*)row)[0];
    unsigned q4 = row[4];
    unpack_bf2(q.x, v[0], v[1]); unpack_bf2(q.y, v[2], v[3]);
    unpack_bf2(q.z, v[4], v[5]); unpack_bf2(q.w, v[6], v[7]);
    unpack_bf2(q4, v[8], v[9]);
}
__device__ __forceinline__ void store_xlb(unsigned* row, const float* v) {
    ((uint4*)row)[0] = make_uint4(pack_bf2(v[0], v[1]), pack_bf2(v[2], v[3]),
                                  pack_bf2(v[4], v[5]), pack_bf2(v[6], v[7]));
    row[4] = pack_bf2(v[8], v[9]);
}
__device__ __forceinline__ void load_row20_bf(const unsigned* row, float* v) {
    const uint4* r4 = (const uint4*)row;
    uint4 q0 = r4[0], q1 = r4[1];
    uint2 q2 = ((const uint2*)row)[4];
    unpack_bf2(q0.x, v[0], v[1]);   unpack_bf2(q0.y, v[2], v[3]);
    unpack_bf2(q0.z, v[4], v[5]);   unpack_bf2(q0.w, v[6], v[7]);
    unpack_bf2(q1.x, v[8], v[9]);   unpack_bf2(q1.y, v[10], v[11]);
    unpack_bf2(q1.z, v[12], v[13]); unpack_bf2(q1.w, v[14], v[15]);
    unpack_bf2(q2.x, v[16], v[17]); unpack_bf2(q2.y, v[18], v[19]);
}
__device__ __forceinline__ void store_row20_bf(unsigned* row, const float* v) {
    uint4* r4 = (uint4*)row;
    r4[0] = make_uint4(pack_bf2(v[0], v[1]), pack_bf2(v[2], v[3]),
                       pack_bf2(v[4], v[5]), pack_bf2(v[6], v[7]));
    r4[1] = make_uint4(pack_bf2(v[8], v[9]), pack_bf2(v[10], v[11]),
                       pack_bf2(v[12], v[13]), pack_bf2(v[14], v[15]));
    r4[2] = make_uint4(pack_bf2(v[16], v[17]), pack_bf2(v[18], v[19]), 0u, 0u);
}

// ---- one edge's contribution (no-max softmax: logits bounded |e| << 88,
// so raw expf cannot overflow; correctness-verified on real data in r4) ----
__device__ __forceinline__ void edge_accum(uint4 qa, unsigned qb,
                                           const float* xr, const float* satt,
                                           float* num, float& den) {
    float xls[10];
    unpack_bf2(qa.x, xls[0], xls[1]); unpack_bf2(qa.y, xls[2], xls[3]);
    unpack_bf2(qa.z, xls[4], xls[5]); unpack_bf2(qa.w, xls[6], xls[7]);
    unpack_bf2(qb, xls[8], xls[9]);
    float acc = 0.f;
#pragma unroll
    for (int k = 0; k < 10; k++) {
        float v = xls[k] + xr[k];
        v = (v > 0.f) ? v : 0.2f * v;
        acc += v * satt[k];
    }
    float w = __expf(acc);
    den += w;
#pragma unroll
    for (int j = 0; j < 10; j++) num[j] += w * xls[j];
}

// ---- shared gather core: depth-2 rolling pipeline (measured best, r2) ----
// index fetched 2 iters ahead, row fetched 1 iter ahead.
__device__ __forceinline__ void gather_core(int n, int sub, const unsigned* xlb,
                                            const float* xr_arr, const float* satt,
                                            const float* sb, float* hout) {
    float xr[10];
    load_row10(&xr_arr[(size_t)n * HS], xr);
    float den = 0.f, num[10];
#pragma unroll
    for (int j = 0; j < 10; j++) num[j] = 0.f;
    if (sub == 0) {   // self-loop
        const unsigned* rp = &xlb[(size_t)n * XLU];
        uint4 qa = ((const uint4*)rp)[0];
        unsigned qb = rp[4];
        edge_accum(qa, qb, xr, satt, num, den);
    }
    int lo = g_off[n], hi = lo + g_cnt[n];
    int e = lo + sub;
    int sCur = (e < hi) ? g_csrc[e] : 0;
    int sNxt = (e + 4 < hi) ? g_csrc[e + 4] : 0;
    uint4 qA; unsigned q4A;
    {
        const unsigned* rp = &xlb[(size_t)sCur * XLU];
        qA = ((const uint4*)rp)[0]; q4A = rp[4];
    }
    while (e < hi) {
        uint4 qa = qA; unsigned qb = q4A;
        // issue next row load (index already resident)
        {
            const unsigned* rp = &xlb[(size_t)sNxt * XLU];
            qA = ((const uint4*)rp)[0]; q4A = rp[4];
        }
        // fetch index two iterations ahead
        sNxt = (e + 8 < hi) ? g_csrc[e + 8] : 0;
        edge_accum(qa, qb, xr, satt, num, den);
        e += 4;
    }
#pragma unroll
    for (int off = 1; off <= 2; off <<= 1) {
        den += __shfl_xor(den, off);
#pragma unroll
        for (int j = 0; j < 10; j++) num[j] += __shfl_xor(num[j], off);
    }
    float inv = 1.f / den;
#pragma unroll
    for (int j = 0; j < 10; j++) {
        float v = num[j] * inv + sb[j];
        hout[j] = (v > 0.f) ? v : 0.f;
    }
}

// ---------------- init ----------------
__global__ void k_init(int M) {
    int i = blockIdx.x * blockDim.x + threadIdx.x;
    int tot = NPART * M;
    if (i < tot) ((float*)g_pp)[i] = 0.f;
    if (i < 256) g_bcnt[i] = 0;
    if (i == tot) g_vsum[0] = 0.f;
}

// ---------------- CSR build ----------------
__global__ void k_bhist(const int* __restrict__ dst, int E) {
    __shared__ int hist[256];
    hist[threadIdx.x] = 0;
    __syncthreads();
    for (int e = blockIdx.x * blockDim.x + threadIdx.x; e < E; e += gridDim.x * blockDim.x)
        atomicAdd(&hist[dst[e] >> BKS], 1);
    __syncthreads();
    int v = hist[threadIdx.x];
    if (v) atomicAdd(&g_bcnt[threadIdx.x], v);
}
__global__ void k_bscan() {
    __shared__ int s[256];
    int t = threadIdx.x;
    int v = g_bcnt[t];
    s[t] = v;
    __syncthreads();
    for (int d = 1; d < 256; d <<= 1) {
        int x = (t >= d) ? s[t - d] : 0;
        __syncthreads();
        s[t] += x;
        __syncthreads();
    }
    g_boff[t] = s[t] - v;
    g_bcur[t] = s[t] - v;
}
__global__ void k_bscatter(const int* __restrict__ src, const int* __restrict__ dst, int E) {
    __shared__ int hist[256], cur[256];
    int lo = blockIdx.x * CHUNK;
    int hi = lo + CHUNK; if (hi > E) hi = E;
    int tid = threadIdx.x;
    hist[tid] = 0;
    __syncthreads();
    for (int e = lo + tid; e < hi; e += 256) atomicAdd(&hist[dst[e] >> BKS], 1);
    __syncthreads();
    int h = hist[tid];
    cur[tid] = h ? atomicAdd(&g_bcur[tid], h) : 0;
    __syncthreads();
    for (int e = lo + tid; e < hi; e += 256) {
        int d = dst[e];
        int pos = atomicAdd(&cur[d >> BKS], 1);
        g_staged[pos] = ((unsigned)src[e] << BKS) | (unsigned)(d & ((1 << BKS) - 1));
    }
}
__global__ void k_bgroup(int N, int E, int nbk) {
    __shared__ int cnt[1024], offl[1024], ssum[512];
    int b = blockIdx.x;
    int nodebase = b << BKS;
    int bstart = g_boff[b];
    int bend = (b + 1 < nbk) ? g_boff[b + 1] : E;
    int tid = threadIdx.x;
    cnt[tid] = 0; cnt[tid + 512] = 0;
    __syncthreads();
    for (int e = bstart + tid; e < bend; e += 512)
        atomicAdd(&cnt[g_staged[e] & 1023u], 1);
    __syncthreads();
    int s0 = cnt[2 * tid], s1 = cnt[2 * tid + 1];
    int tsum = s0 + s1;
    ssum[tid] = tsum;
    __syncthreads();
    for (int d = 1; d < 512; d <<= 1) {
        int x = (tid >= d) ? ssum[tid - d] : 0;
        __syncthreads();
        ssum[tid] += x;
        __syncthreads();
    }
    int base = ssum[tid] - tsum;
    offl[2 * tid] = base;
    offl[2 * tid + 1] = base + s0;
    __syncthreads();
    int n0 = nodebase + 2 * tid, n1 = n0 + 1;
    if (n0 < N) { g_off[n0] = bstart + offl[2 * tid]; g_cnt[n0] = s0; }
    if (n1 < N) { g_off[n1] = bstart + offl[2 * tid + 1]; g_cnt[n1] = s1; }
    cnt[2 * tid] = offl[2 * tid];
    cnt[2 * tid + 1] = offl[2 * tid + 1];
    __syncthreads();
    for (int e = bstart + tid; e < bend; e += 512) {
        unsigned w = g_staged[e];
        int p = atomicAdd(&cnt[w & 1023u], 1);
        g_csrc[bstart + p] = (int)(w >> BKS);
    }
}

// ---- layer-1 pre ----
__global__ void k_pre1(const float* __restrict__ x1,
                       const float* __restrict__ wl, const float* __restrict__ wr, int N) {
    __shared__ float swl[150], swr[150];
    for (int t = threadIdx.x; t < 150; t += blockDim.x) { swl[t] = wl[t]; swr[t] = wr[t]; }
    __syncthreads();
    int n = blockIdx.x * blockDim.x + threadIdx.x;
    if (n >= N) return;
    float aL[10], aR[10];
#pragma unroll
    for (int j = 0; j < 10; j++) { aL[j] = 0.f; aR[j] = 0.f; }
    for (int k = 0; k < 15; k++) {
        float v = x1[(size_t)n * 15 + k];
#pragma unroll
        for (int j = 0; j < 10; j++) { aL[j] += v * swl[k * 10 + j]; aR[j] += v * swr[k * 10 + j]; }
    }
    store_xlb(&g_xlbA[(size_t)n * XLU], aL);
#pragma unroll
    for (int j = 0; j < 10; j++) g_xrA[(size_t)n * HS + j] = aR[j];
}

// ---- fused gather(L) + pre(L+1) ----
__global__ void k_gather_pre(const float* __restrict__ x1,
                             const float* __restrict__ att, const float* __restrict__ b,
                             const float* __restrict__ wl, const float* __restrict__ wr,
                             int sel_in, int N) {
    __shared__ float satt[10], sb[10], swl[250], swr[250];
    if (threadIdx.x < 10) { satt[threadIdx.x] = att[threadIdx.x]; sb[threadIdx.x] = b[threadIdx.x]; }
    for (int t = threadIdx.x; t < 250; t += blockDim.x) { swl[t] = wl[t]; swr[t] = wr[t]; }
    __syncthreads();
    int t = blockIdx.x * blockDim.x + threadIdx.x;
    int n = t >> 2, sub = t & 3;
    if (n >= N) return;
    const unsigned* xlb = xlb_buf(sel_in);
    const float* xr_arr = xr_buf(sel_in);
    unsigned* xlb_o = xlb_buf(1 - sel_in);
    float* xr_o = xr_buf(1 - sel_in);
    float h[10];
    gather_core(n, sub, xlb, xr_arr, satt, sb, h);
    if (sub == 0) {
        float aL[10], aR[10];
#pragma unroll
        for (int j = 0; j < 10; j++) { aL[j] = 0.f; aR[j] = 0.f; }
        for (int k = 0; k < 10; k++) {
            float v = h[k];
#pragma unroll
            for (int j = 0; j < 10; j++) { aL[j] += v * swl[k * 10 + j]; aR[j] += v * swr[k * 10 + j]; }
        }
        for (int k = 0; k < 15; k++) {
            float v = x1[(size_t)n * 15 + k];
#pragma unroll
            for (int j = 0; j < 10; j++) { aL[j] += v * swl[(10 + k) * 10 + j]; aR[j] += v * swr[(10 + k) * 10 + j]; }
        }
        store_xlb(&xlb_o[(size_t)n * XLU], aL);
#pragma unroll
        for (int j = 0; j < 10; j++) xr_o[(size_t)n * HS + j] = aR[j];
    }
}

// ---- final gather (layer 3): writes h ----
__global__ void k_gather3(const float* __restrict__ att, const float* __restrict__ b,
                          int sel_in, int N) {
    __shared__ float satt[10], sb[10];
    if (threadIdx.x < 10) { satt[threadIdx.x] = att[threadIdx.x]; sb[threadIdx.x] = b[threadIdx.x]; }
    __syncthreads();
    int t = blockIdx.x * blockDim.x + threadIdx.x;
    int n = t >> 2, sub = t & 3;
    if (n >= N) return;
    float h[10];
    gather_core(n, sub, xlb_buf(sel_in), xr_buf(sel_in), satt, sb, h);
    if (sub == 0) {
#pragma unroll
        for (int j = 0; j < 10; j++) g_h[(size_t)n * HS + j] = h[j];
    }
}

// ---- fused: pre-project u-rows (bf16) + value head partial sum ----
// __launch_bounds__(256,1): ~110 live floats/thread -> needs >=128 VGPRs.
__global__ void __launch_bounds__(256, 1)
k_prep_value(const float* __restrict__ x1,
             const float* __restrict__ aw, const float* __restrict__ cw,
             const float* __restrict__ x2,
             const float* __restrict__ w1, const float* __restrict__ b1,
             const float* __restrict__ w2, const float* __restrict__ bias2,
             int N) {
    __shared__ float sA[48 * 20], sC[23 * 20], sw1[29 * 15];
    __shared__ float sb1[15], sw2v[15], sx2[4], sb2v;
    __shared__ float red[256];
    for (int t = threadIdx.x; t < 48 * 20; t += blockDim.x) sA[t] = aw[t];
    for (int t = threadIdx.x; t < 23 * 20; t += blockDim.x) sC[t] = cw[t];
    for (int t = threadIdx.x; t < 29 * 15; t += blockDim.x) sw1[t] = w1[t];
    if (threadIdx.x < 15) { sb1[threadIdx.x] = b1[threadIdx.x]; sw2v[threadIdx.x] = w2[threadIdx.x]; }
    if (threadIdx.x < 4) sx2[threadIdx.x] = x2[threadIdx.x];
    if (threadIdx.x == 0) sb2v = bias2[0];
    __syncthreads();
    int n = blockIdx.x * blockDim.x + threadIdx.x;
    float vout = 0.f;
    if (n < N) {
        float hv[10], xv[15];
        load_row10(&g_h[(size_t)n * HS], hv);
#pragma unroll
        for (int k = 0; k < 15; k++) xv[k] = x1[(size_t)n * 15 + k];
        float us[20], ud[20], ut[20];
#pragma unroll
        for (int j = 0; j < 20; j++) { us[j] = 0.f; ud[j] = 0.f; ut[j] = 0.f; }
        for (int k = 0; k < 10; k++) {
            float h = hv[k];
#pragma unroll
            for (int j = 0; j < 20; j++) {
                us[j] += h * sA[k * 20 + j];
                ud[j] += h * sA[(10 + k) * 20 + j];
                ut[j] += h * sC[k * 20 + j];
            }
        }
        for (int k = 0; k < 12; k++) {
            float v = xv[3 + k];
#pragma unroll
            for (int j = 0; j < 20; j++) {
                us[j] += v * sA[(20 + k) * 20 + j];
                ut[j] += v * sC[(10 + k) * 20 + j];
            }
        }
        for (int k = 0; k < 14; k++) {
            float v = xv[1 + k];
#pragma unroll
            for (int j = 0; j < 20; j++) ud[j] += v * sA[(32 + k) * 20 + j];
        }
        float t34 = -0.7f * (xv[3] + xv[4]);
#pragma unroll
        for (int j = 0; j < 20; j++) ud[j] += t34 * sA[47 * 20 + j];
        store_row20_bf(&g_us[(size_t)n * USU], us);
        store_row20_bf(&g_ud[(size_t)n * USU], ud);
        store_row20_bf(&g_ut[(size_t)n * USU], ut);
        float acc[15];
#pragma unroll
        for (int j = 0; j < 15; j++) acc[j] = sb1[j];
        for (int k = 0; k < 10; k++) {
            float f = hv[k];
#pragma unroll
            for (int j = 0; j < 15; j++) acc[j] += f * sw1[k * 15 + j];
        }
        for (int k = 0; k < 15; k++) {
            float f = xv[k];
#pragma unroll
            for (int j = 0; j < 15; j++) acc[j] += f * sw1[(10 + k) * 15 + j];
        }
        for (int k = 0; k < 4; k++) {
            float f = sx2[k];
#pragma unroll
            for (int j = 0; j < 15; j++) acc[j] += f * sw1[(25 + k) * 15 + j];
        }
        vout = sb2v;
#pragma unroll
        for (int j = 0; j < 15; j++) { float r = (acc[j] > 0.f) ? acc[j] : 0.f; vout += r * sw2v[j]; }
    }
    red[threadIdx.x] = vout;
    __syncthreads();
    for (int s = 128; s > 0; s >>= 1) {
        if (threadIdx.x < (unsigned)s) red[threadIdx.x] += red[threadIdx.x + s];
        __syncthreads();
    }
    if (threadIdx.x == 0) atomicAdd(&g_vsum[0], red[0]);
}

// ---- attack scoring (1 item/thread; split from deploy for profile visibility) ----
__global__ void k_score_a(const int* __restrict__ asrc, const int* __restrict__ adst,
                          const float* __restrict__ aarm, const int* __restrict__ amove,
                          const float* __restrict__ aw, const float* __restrict__ ab,
                          const float* __restrict__ bw, const float* __restrict__ bb,
                          int Ma) {
    __shared__ float swa[20], sbias[20], sw2[20], sb2;
    float* pp = g_pp[blockIdx.x & (NPART - 1)];
    if (threadIdx.x < 20) {
        swa[threadIdx.x] = aw[46 * 20 + threadIdx.x] + 0.6f * aw[47 * 20 + threadIdx.x];
        sbias[threadIdx.x] = ab[threadIdx.x];
        sw2[threadIdx.x] = bw[threadIdx.x];
    }
    if (threadIdx.x == 0) sb2 = bb[0];
    __syncthreads();
    int i = blockIdx.x * blockDim.x + threadIdx.x;
    if (i >= Ma) return;
    int s = asrc[i], d = adst[i];
    float a = aarm[i];
    float us[20], ud[20];
    load_row20_bf(&g_us[(size_t)s * USU], us);
    load_row20_bf(&g_ud[(size_t)d * USU], ud);
    float sres = sb2;
#pragma unroll
    for (int j = 0; j < 20; j++) {
        float acc = sbias[j] + us[j] + ud[j] + a * swa[j];
        float r = (acc > 0.f) ? acc : 0.f;
        sres += r * sw2[j];
    }
    atomicAdd(&pp[amove[i]], sres);
}

// ---- deploy scoring ----
__global__ void k_score_d(const int* __restrict__ dtar, const float* __restrict__ darm,
                          const int* __restrict__ dmove,
                          const float* __restrict__ cw, const float* __restrict__ cb,
                          const float* __restrict__ dw, const float* __restrict__ db,
                          int Md) {
    __shared__ float swa[20], sbias[20], sw2[20], sb2;
    float* pp = g_pp[blockIdx.x & (NPART - 1)];
    if (threadIdx.x < 20) {
        swa[threadIdx.x] = cw[22 * 20 + threadIdx.x];
        sbias[threadIdx.x] = cb[threadIdx.x];
        sw2[threadIdx.x] = dw[threadIdx.x];
    }
    if (threadIdx.x == 0) sb2 = db[0];
    __syncthreads();
    int i = blockIdx.x * blockDim.x + threadIdx.x;
    if (i >= Md) return;
    int t = dtar[i];
    float a = darm[i];
    float ut[20];
    load_row20_bf(&g_ut[(size_t)t * USU], ut);
    float sres = sb2;
#pragma unroll
    for (int j = 0; j < 20; j++) {
        float acc = sbias[j] + ut[j] + a * swa[j];
        float r = (acc > 0.f) ? acc : 0.f;
        sres += r * sw2[j];
    }
    atomicAdd(&pp[dmove[i]], sres);
}

// -------- finalize (parallel): reduce partials + per-block online-softmax stats --------
__global__ void k_reduce(int M) {
    __shared__ float red[256];
    int i = blockIdx.x * 256 + threadIdx.x;
    float s = -1e30f;
    if (i < M) {
        float t = 0.f;
#pragma unroll
        for (int q = 0; q < NPART; q++) t += g_pp[q][i];
        g_p[i] = t;
        s = t;
    }
    red[threadIdx.x] = s;
    __syncthreads();
    for (int d = 128; d > 0; d >>= 1) {
        if (threadIdx.x < d) red[threadIdx.x] = fmaxf(red[threadIdx.x], red[threadIdx.x + d]);
        __syncthreads();
    }
    float bmax = red[0];
    __syncthreads();
    red[threadIdx.x] = (i < M) ? __expf(s - bmax) : 0.f;
    __syncthreads();
    for (int d = 128; d > 0; d >>= 1) {
        if (threadIdx.x < d) red[threadIdx.x] += red[threadIdx.x + d];
        __syncthreads();
    }
    if (threadIdx.x == 0) { g_bmax[blockIdx.x] = bmax; g_bsum[blockIdx.x] = red[0]; }
}

__global__ void k_lse(float* __restrict__ out, int N, int nrb) {
    __shared__ float rm[256], rs[256];
    int tid = threadIdx.x;
    float mx = -1e30f;
    for (int i = tid; i < nrb; i += 256) mx = fmaxf(mx, g_bmax[i]);
    rm[tid] = mx;
    __syncthreads();
    for (int d = 128; d > 0; d >>= 1) {
        if (tid < d) rm[tid] = fmaxf(rm[tid], rm[tid + d]);
        __syncthreads();
    }
    float pmax = rm[0];
    __syncthreads();
    float sm = 0.f;
    for (int i = tid; i < nrb; i += 256) sm += g_bsum[i] * __expf(g_bmax[i] - pmax);
    rs[tid] = sm;
    __syncthreads();
    for (int d = 128; d > 0; d >>= 1) {
        if (tid < d) rs[tid] += rs[tid + d];
        __syncthreads();
    }
    if (tid == 0) {
        g_lse[0] = pmax + logf(rs[0]);
        out[0] = tanhf(g_vsum[0] / (float)N);
    }
}

__global__ void k_write(float* __restrict__ out, int M) {
    int i = blockIdx.x * 256 + threadIdx.x;
    if (i < M) out[1 + i] = g_p[i] - g_lse[0];
}

extern "C" void kernel_launch(void* const* d_in, const int* in_sizes, int n_in,
                              void* d_out, int out_size, void* d_ws, size_t ws_size,
                              hipStream_t stream) {
    const float* x1 = (const float*)d_in[0];
    const float* x2 = (const float*)d_in[1];
    const int* edges = (const int*)d_in[2];
    const int* asrc = (const int*)d_in[3];
    const int* adst = (const int*)d_in[4];
    const float* aarm = (const float*)d_in[5];
    const int* amove = (const int*)d_in[6];
    const int* dtar = (const int*)d_in[7];
    const float* darm = (const float*)d_in[8];
    const int* dmove = (const int*)d_in[9];
    const int pb = n_in - 24;
    const float* g1_wl  = (const float*)d_in[pb + 0];
    const float* g1_wr  = (const float*)d_in[pb + 1];
    const float* g1_att = (const float*)d_in[pb + 2];
    const float* g1_b   = (const float*)d_in[pb + 3];
    const float* g2_wl  = (const float*)d_in[pb + 4];
    const float* g2_wr  = (const float*)d_in[pb + 5];
    const float* g2_att = (const float*)d_in[pb + 6];
    const float* g2_b   = (const float*)d_in[pb + 7];
    const float* g3_wl  = (const float*)d_in[pb + 8];
    const float* g3_wr  = (const float*)d_in[pb + 9];
    const float* g3_att = (const float*)d_in[pb + 10];
    const float* g3_b   = (const float*)d_in[pb + 11];
    const float* lin_w  = (const float*)d_in[pb + 12];
    const float* lin_b  = (const float*)d_in[pb + 13];
    const float* lin2_w = (const float*)d_in[pb + 14];
    const float* lin2_b = (const float*)d_in[pb + 15];
    const float* aaa_w  = (const float*)d_in[pb + 16];
    const float* aaa_b  = (const float*)d_in[pb + 17];
    const float* bbb_w  = (const float*)d_in[pb + 18];
    const float* bbb_b  = (const float*)d_in[pb + 19];
    const float* ccc_w  = (const float*)d_in[pb + 20];
    const float* ccc_b  = (const float*)d_in[pb + 21];
    const float* ddd_w  = (const float*)d_in[pb + 22];
    const float* ddd_b  = (const float*)d_in[pb + 23];

    int N = in_sizes[0] / 15;
    int E = in_sizes[2] / 2;
    const int Ma = in_sizes[3];
    const int Md = in_sizes[7];
    int M = out_size - 1;
    if (N > N_CAP) N = N_CAP;
    if (E > E_CAP) E = E_CAP;
    if (M > M_CAP) M = M_CAP;
    const int* src = edges;
    const int* dst = edges + E;

    const int nb = (N + 255) / 256;
    const int nb4 = (4 * N + 255) / 256;
    const int nbk = (N + (1 << BKS) - 1) >> BKS;
    const int nsc = (E + CHUNK - 1) / CHUNK;
    const int na = (Ma + 255) / 256, nd = (Md + 255) / 256;
    const int nrb = (M + 255) / 256;

    // init + CSR build (once; reused by all 3 layers)
    k_init<<<(NPART * M + 256) / 256, 256, 0, stream>>>(M);
    k_bhist<<<512, 256, 0, stream>>>(dst, E);
    k_bscan<<<1, 256, 0, stream>>>();
    k_bscatter<<<nsc, 256, 0, stream>>>(src, dst, E);
    k_bgroup<<<nbk, 512, 0, stream>>>(N, E, nbk);

    // GAT layers: pre1 -> A; gather1+pre2 -> B; gather2+pre3 -> A; gather3 -> h
    k_pre1<<<nb, 256, 0, stream>>>(x1, g1_wl, g1_wr, N);
    k_gather_pre<<<nb4, 256, 0, stream>>>(x1, g1_att, g1_b, g2_wl, g2_wr, 0, N);
    k_gather_pre<<<nb4, 256, 0, stream>>>(x1, g2_att, g2_b, g3_wl, g3_wr, 1, N);
    k_gather3<<<nb4, 256, 0, stream>>>(g3_att, g3_b, 0, N);

    // u-row projection + value head, attack/deploy scoring, finalize
    k_prep_value<<<nb, 256, 0, stream>>>(x1, aaa_w, ccc_w, x2, lin_w, lin_b, lin2_w, lin2_b, N);
    k_score_a<<<na, 256, 0, stream>>>(asrc, adst, aarm, amove, aaa_w, aaa_b, bbb_w, bbb_b, Ma);
    k_score_d<<<nd, 256, 0, stream>>>(dtar, darm, dmove, ccc_w, ccc_b, ddd_w, ddd_b, Md);
    k_reduce<<<nrb, 256, 0, stream>>>(M);
    k_lse<<<1, 256, 0, stream>>>((float*)d_out, N, nrb);
    k_write<<<nrb, 256, 0, stream>>>((float*)d_out, M);
}

// Round 6
// 512.129 us; speedup vs baseline: 1.0874x; 1.0532x over previous
//
#include <hip/hip_runtime.h>
#include <hip/hip_bf16.h>

#define HS 12       // stride for h / xr rows (48B)
#define XLU 5       // stride (uints) for bf16 xl rows (20B packed -> 4.0MB array, per-XCD-L2-resident)
#define USU 12      // stride (uints) for packed bf16 u-rows (48B; 64B stride regressed: cache footprint > line-split win)
#define NPART 8     // p-histogram partitions
#define N_CAP 200000
#define M_CAP 32768
#define E_CAP 3200000
#define BKS 10      // 1024 nodes per bucket (196 buckets)
#define SCAPL 15    // per-bucket capacity log2 (32768 slots; mean fill ~16.3K, P(overflow)~0)
#define NBK_CAP ((N_CAP + (1 << BKS) - 1) >> BKS)
#define CHUNK 6144  // edges per k_bscatter block

// Static device scratch
__device__ __align__(32) unsigned g_xlbA[(size_t)N_CAP * XLU];
__device__ __align__(32) unsigned g_xlbB[(size_t)N_CAP * XLU];
__device__ __align__(16) float    g_xrA[(size_t)N_CAP * HS];
__device__ __align__(16) float    g_xrB[(size_t)N_CAP * HS];
__device__ __align__(16) float    g_h [(size_t)N_CAP * HS];
__device__ __align__(16) unsigned g_us[(size_t)N_CAP * USU];
__device__ __align__(16) unsigned g_ud[(size_t)N_CAP * USU];
__device__ __align__(16) unsigned g_ut[(size_t)N_CAP * USU];
__device__ int      g_cnt[N_CAP];
__device__ int      g_off[N_CAP];
__device__ int      g_bcur[256];
__device__ unsigned g_staged[(size_t)NBK_CAP << SCAPL];
__device__ int      g_csrc[(size_t)NBK_CAP << SCAPL];
__device__ __align__(64) float g_pp[NPART][M_CAP];
__device__ float    g_p[M_CAP];
__device__ float    g_vsum[1];
__device__ float    g_bmax[M_CAP / 256];
__device__ float    g_bsum[M_CAP / 256];
__device__ float    g_lse[1];

__device__ __forceinline__ unsigned* xlb_buf(int s) { return s ? g_xlbB : g_xlbA; }
__device__ __forceinline__ float*    xr_buf(int s)  { return s ? g_xrB : g_xrA; }

__device__ __forceinline__ void load_row10(const float* row, float* v) {
    const float4* r4 = (const float4*)row;
    float4 a = r4[0], b = r4[1];
    float2 c = ((const float2*)row)[4];
    v[0] = a.x; v[1] = a.y; v[2] = a.z; v[3] = a.w;
    v[4] = b.x; v[5] = b.y; v[6] = b.z; v[7] = b.w;
    v[8] = c.x; v[9] = c.y;
}
__device__ __forceinline__ unsigned pack_bf2(float a, float b) {
    unsigned ua = __float_as_uint(a); ua = (ua + 0x7fffu + ((ua >> 16) & 1u)) >> 16;
    unsigned ub = __float_as_uint(b); ub = (ub + 0x7fffu + ((ub >> 16) & 1u)) >> 16;
    return ua | (ub << 16);
}
__device__ __forceinline__ void unpack_bf2(unsigned u, float& a, float& b) {
    a = __uint_as_float(u << 16);
    b = __uint_as_float(u & 0xffff0000u);
}
// xl rows are 20B at 4B alignment: dwordx4 (legal at 4B align on gfx950) + dword.
__device__ __forceinline__ void load_xlb(const unsigned* row, float* v) {
    uint4 q = ((const uint4*)row)[0];
    unsigned q4 = row[4];
    unpack_bf2(q.x, v[0], v[1]); unpack_bf2(q.y, v[2], v[3]);
    unpack_bf2(q.z, v[4], v[5]); unpack_bf2(q.w, v[6], v[7]);
    unpack_bf2(q4, v[8], v[9]);
}
__device__ __forceinline__ void store_xlb(unsigned* row, const float* v) {
    ((uint4*)row)[0] = make_uint4(pack_bf2(v[0], v[1]), pack_bf2(v[2], v[3]),
                                  pack_bf2(v[4], v[5]), pack_bf2(v[6], v[7]));
    row[4] = pack_bf2(v[8], v[9]);
}
__device__ __forceinline__ void load_row20_bf(const unsigned* row, float* v) {
    const uint4* r4 = (const uint4*)row;
    uint4 q0 = r4[0], q1 = r4[1];
    uint2 q2 = ((const uint2*)row)[4];
    unpack_bf2(q0.x, v[0], v[1]);   unpack_bf2(q0.y, v[2], v[3]);
    unpack_bf2(q0.z, v[4], v[5]);   unpack_bf2(q0.w, v[6], v[7]);
    unpack_bf2(q1.x, v[8], v[9]);   unpack_bf2(q1.y, v[10], v[11]);
    unpack_bf2(q1.z, v[12], v[13]); unpack_bf2(q1.w, v[14], v[15]);
    unpack_bf2(q2.x, v[16], v[17]); unpack_bf2(q2.y, v[18], v[19]);
}
__device__ __forceinline__ void store_row20_bf(unsigned* row, const float* v) {
    uint4* r4 = (uint4*)row;
    r4[0] = make_uint4(pack_bf2(v[0], v[1]), pack_bf2(v[2], v[3]),
                       pack_bf2(v[4], v[5]), pack_bf2(v[6], v[7]));
    r4[1] = make_uint4(pack_bf2(v[8], v[9]), pack_bf2(v[10], v[11]),
                       pack_bf2(v[12], v[13]), pack_bf2(v[14], v[15]));
    r4[2] = make_uint4(pack_bf2(v[16], v[17]), pack_bf2(v[18], v[19]), 0u, 0u);
}

// ---- one edge's contribution (no-max softmax: logits bounded |e| << 88,
// so raw expf cannot overflow; correctness-verified on real data in r4/r5) ----
__device__ __forceinline__ void edge_accum(uint4 qa, unsigned qb,
                                           const float* xr, const float* satt,
                                           float* num, float& den) {
    float xls[10];
    unpack_bf2(qa.x, xls[0], xls[1]); unpack_bf2(qa.y, xls[2], xls[3]);
    unpack_bf2(qa.z, xls[4], xls[5]); unpack_bf2(qa.w, xls[6], xls[7]);
    unpack_bf2(qb, xls[8], xls[9]);
    float acc = 0.f;
#pragma unroll
    for (int k = 0; k < 10; k++) {
        float v = xls[k] + xr[k];
        v = (v > 0.f) ? v : 0.2f * v;
        acc += v * satt[k];
    }
    float w = __expf(acc);
    den += w;
#pragma unroll
    for (int j = 0; j < 10; j++) num[j] += w * xls[j];
}

// ---- shared gather core: depth-2 rolling pipeline (measured best, r2) ----
__device__ __forceinline__ void gather_core(int n, int sub, const unsigned* xlb,
                                            const float* xr_arr, const float* satt,
                                            const float* sb, float* hout) {
    float xr[10];
    load_row10(&xr_arr[(size_t)n * HS], xr);
    float den = 0.f, num[10];
#pragma unroll
    for (int j = 0; j < 10; j++) num[j] = 0.f;
    if (sub == 0) {   // self-loop
        const unsigned* rp = &xlb[(size_t)n * XLU];
        uint4 qa = ((const uint4*)rp)[0];
        unsigned qb = rp[4];
        edge_accum(qa, qb, xr, satt, num, den);
    }
    int lo = g_off[n], hi = lo + g_cnt[n];
    int e = lo + sub;
    int sCur = (e < hi) ? g_csrc[e] : 0;
    int sNxt = (e + 4 < hi) ? g_csrc[e + 4] : 0;
    uint4 qA; unsigned q4A;
    {
        const unsigned* rp = &xlb[(size_t)sCur * XLU];
        qA = ((const uint4*)rp)[0]; q4A = rp[4];
    }
    while (e < hi) {
        uint4 qa = qA; unsigned qb = q4A;
        {
            const unsigned* rp = &xlb[(size_t)sNxt * XLU];
            qA = ((const uint4*)rp)[0]; q4A = rp[4];
        }
        sNxt = (e + 8 < hi) ? g_csrc[e + 8] : 0;
        edge_accum(qa, qb, xr, satt, num, den);
        e += 4;
    }
#pragma unroll
    for (int off = 1; off <= 2; off <<= 1) {
        den += __shfl_xor(den, off);
#pragma unroll
        for (int j = 0; j < 10; j++) num[j] += __shfl_xor(num[j], off);
    }
    float inv = 1.f / den;
#pragma unroll
    for (int j = 0; j < 10; j++) {
        float v = num[j] * inv + sb[j];
        hout[j] = (v > 0.f) ? v : 0.f;
    }
}

// ---------------- init (also zeroes bucket cursors for single-pass CSR) ----------------
__global__ void k_init(int M) {
    int i = blockIdx.x * blockDim.x + threadIdx.x;
    int tot = NPART * M;
    if (i < tot) ((float*)g_pp)[i] = 0.f;
    if (i < 256) g_bcur[i] = 0;
    if (i == tot) g_vsum[0] = 0.f;
}

// ---------------- CSR build (single-pass: fixed 32K-slot bucket regions) ----------------
// Bucket append order is arbitrary; k_bgroup re-sorts by node within each bucket.
__global__ void k_bscatter(const int* __restrict__ src, const int* __restrict__ dst, int E) {
    __shared__ int hist[256], cur[256];
    int lo = blockIdx.x * CHUNK;
    int hi = lo + CHUNK; if (hi > E) hi = E;
    int tid = threadIdx.x;
    hist[tid] = 0;
    __syncthreads();
    for (int e = lo + tid; e < hi; e += 256) atomicAdd(&hist[dst[e] >> BKS], 1);
    __syncthreads();
    int h = hist[tid];
    cur[tid] = h ? atomicAdd(&g_bcur[tid], h) : 0;
    __syncthreads();
    for (int e = lo + tid; e < hi; e += 256) {
        int d = dst[e];
        int b = d >> BKS;
        int pos = atomicAdd(&cur[b], 1);
        g_staged[((size_t)b << SCAPL) + pos] =
            ((unsigned)src[e] << BKS) | (unsigned)(d & ((1 << BKS) - 1));
    }
}
__global__ void k_bgroup(int N, int nbk) {
    __shared__ int cnt[1024], offl[1024], ssum[512];
    int b = blockIdx.x;
    int nodebase = b << BKS;
    int bstart = b << SCAPL;
    int bend = bstart + g_bcur[b];
    int tid = threadIdx.x;
    cnt[tid] = 0; cnt[tid + 512] = 0;
    __syncthreads();
    for (int e = bstart + tid; e < bend; e += 512)
        atomicAdd(&cnt[g_staged[e] & 1023u], 1);
    __syncthreads();
    int s0 = cnt[2 * tid], s1 = cnt[2 * tid + 1];
    int tsum = s0 + s1;
    ssum[tid] = tsum;
    __syncthreads();
    for (int d = 1; d < 512; d <<= 1) {
        int x = (tid >= d) ? ssum[tid - d] : 0;
        __syncthreads();
        ssum[tid] += x;
        __syncthreads();
    }
    int base = ssum[tid] - tsum;
    offl[2 * tid] = base;
    offl[2 * tid + 1] = base + s0;
    __syncthreads();
    int n0 = nodebase + 2 * tid, n1 = n0 + 1;
    if (n0 < N) { g_off[n0] = bstart + offl[2 * tid]; g_cnt[n0] = s0; }
    if (n1 < N) { g_off[n1] = bstart + offl[2 * tid + 1]; g_cnt[n1] = s1; }
    cnt[2 * tid] = offl[2 * tid];
    cnt[2 * tid + 1] = offl[2 * tid + 1];
    __syncthreads();
    for (int e = bstart + tid; e < bend; e += 512) {
        unsigned w = g_staged[e];
        int p = atomicAdd(&cnt[w & 1023u], 1);
        g_csrc[bstart + p] = (int)(w >> BKS);
    }
}

// ---- layer-1 pre ----
__global__ void k_pre1(const float* __restrict__ x1,
                       const float* __restrict__ wl, const float* __restrict__ wr, int N) {
    __shared__ float swl[150], swr[150];
    for (int t = threadIdx.x; t < 150; t += blockDim.x) { swl[t] = wl[t]; swr[t] = wr[t]; }
    __syncthreads();
    int n = blockIdx.x * blockDim.x + threadIdx.x;
    if (n >= N) return;
    float aL[10], aR[10];
#pragma unroll
    for (int j = 0; j < 10; j++) { aL[j] = 0.f; aR[j] = 0.f; }
    for (int k = 0; k < 15; k++) {
        float v = x1[(size_t)n * 15 + k];
#pragma unroll
        for (int j = 0; j < 10; j++) { aL[j] += v * swl[k * 10 + j]; aR[j] += v * swr[k * 10 + j]; }
    }
    store_xlb(&g_xlbA[(size_t)n * XLU], aL);
#pragma unroll
    for (int j = 0; j < 10; j++) g_xrA[(size_t)n * HS + j] = aR[j];
}

// ---- fused gather(L) + pre(L+1) ----
__global__ void k_gather_pre(const float* __restrict__ x1,
                             const float* __restrict__ att, const float* __restrict__ b,
                             const float* __restrict__ wl, const float* __restrict__ wr,
                             int sel_in, int N) {
    __shared__ float satt[10], sb[10], swl[250], swr[250];
    if (threadIdx.x < 10) { satt[threadIdx.x] = att[threadIdx.x]; sb[threadIdx.x] = b[threadIdx.x]; }
    for (int t = threadIdx.x; t < 250; t += blockDim.x) { swl[t] = wl[t]; swr[t] = wr[t]; }
    __syncthreads();
    int t = blockIdx.x * blockDim.x + threadIdx.x;
    int n = t >> 2, sub = t & 3;
    if (n >= N) return;
    const unsigned* xlb = xlb_buf(sel_in);
    const float* xr_arr = xr_buf(sel_in);
    unsigned* xlb_o = xlb_buf(1 - sel_in);
    float* xr_o = xr_buf(1 - sel_in);
    float h[10];
    gather_core(n, sub, xlb, xr_arr, satt, sb, h);
    if (sub == 0) {
        float aL[10], aR[10];
#pragma unroll
        for (int j = 0; j < 10; j++) { aL[j] = 0.f; aR[j] = 0.f; }
        for (int k = 0; k < 10; k++) {
            float v = h[k];
#pragma unroll
            for (int j = 0; j < 10; j++) { aL[j] += v * swl[k * 10 + j]; aR[j] += v * swr[k * 10 + j]; }
        }
        for (int k = 0; k < 15; k++) {
            float v = x1[(size_t)n * 15 + k];
#pragma unroll
            for (int j = 0; j < 10; j++) { aL[j] += v * swl[(10 + k) * 10 + j]; aR[j] += v * swr[(10 + k) * 10 + j]; }
        }
        store_xlb(&xlb_o[(size_t)n * XLU], aL);
#pragma unroll
        for (int j = 0; j < 10; j++) xr_o[(size_t)n * HS + j] = aR[j];
    }
}

// ---- final gather (layer 3): writes h ----
__global__ void k_gather3(const float* __restrict__ att, const float* __restrict__ b,
                          int sel_in, int N) {
    __shared__ float satt[10], sb[10];
    if (threadIdx.x < 10) { satt[threadIdx.x] = att[threadIdx.x]; sb[threadIdx.x] = b[threadIdx.x]; }
    __syncthreads();
    int t = blockIdx.x * blockDim.x + threadIdx.x;
    int n = t >> 2, sub = t & 3;
    if (n >= N) return;
    float h[10];
    gather_core(n, sub, xlb_buf(sel_in), xr_buf(sel_in), satt, sb, h);
    if (sub == 0) {
#pragma unroll
        for (int j = 0; j < 10; j++) g_h[(size_t)n * HS + j] = h[j];
    }
}

// ---- fused: pre-project u-rows (bf16) + value head partial sum ----
__global__ void __launch_bounds__(256, 1)
k_prep_value(const float* __restrict__ x1,
             const float* __restrict__ aw, const float* __restrict__ cw,
             const float* __restrict__ x2,
             const float* __restrict__ w1, const float* __restrict__ b1,
             const float* __restrict__ w2, const float* __restrict__ bias2,
             int N) {
    __shared__ float sA[48 * 20], sC[23 * 20], sw1[29 * 15];
    __shared__ float sb1[15], sw2v[15], sx2[4], sb2v;
    __shared__ float red[256];
    for (int t = threadIdx.x; t < 48 * 20; t += blockDim.x) sA[t] = aw[t];
    for (int t = threadIdx.x; t < 23 * 20; t += blockDim.x) sC[t] = cw[t];
    for (int t = threadIdx.x; t < 29 * 15; t += blockDim.x) sw1[t] = w1[t];
    if (threadIdx.x < 15) { sb1[threadIdx.x] = b1[threadIdx.x]; sw2v[threadIdx.x] = w2[threadIdx.x]; }
    if (threadIdx.x < 4) sx2[threadIdx.x] = x2[threadIdx.x];
    if (threadIdx.x == 0) sb2v = bias2[0];
    __syncthreads();
    int n = blockIdx.x * blockDim.x + threadIdx.x;
    float vout = 0.f;
    if (n < N) {
        float hv[10], xv[15];
        load_row10(&g_h[(size_t)n * HS], hv);
#pragma unroll
        for (int k = 0; k < 15; k++) xv[k] = x1[(size_t)n * 15 + k];
        float us[20], ud[20], ut[20];
#pragma unroll
        for (int j = 0; j < 20; j++) { us[j] = 0.f; ud[j] = 0.f; ut[j] = 0.f; }
        for (int k = 0; k < 10; k++) {
            float h = hv[k];
#pragma unroll
            for (int j = 0; j < 20; j++) {
                us[j] += h * sA[k * 20 + j];
                ud[j] += h * sA[(10 + k) * 20 + j];
                ut[j] += h * sC[k * 20 + j];
            }
        }
        for (int k = 0; k < 12; k++) {
            float v = xv[3 + k];
#pragma unroll
            for (int j = 0; j < 20; j++) {
                us[j] += v * sA[(20 + k) * 20 + j];
                ut[j] += v * sC[(10 + k) * 20 + j];
            }
        }
        for (int k = 0; k < 14; k++) {
            float v = xv[1 + k];
#pragma unroll
            for (int j = 0; j < 20; j++) ud[j] += v * sA[(32 + k) * 20 + j];
        }
        float t34 = -0.7f * (xv[3] + xv[4]);
#pragma unroll
        for (int j = 0; j < 20; j++) ud[j] += t34 * sA[47 * 20 + j];
        store_row20_bf(&g_us[(size_t)n * USU], us);
        store_row20_bf(&g_ud[(size_t)n * USU], ud);
        store_row20_bf(&g_ut[(size_t)n * USU], ut);
        float acc[15];
#pragma unroll
        for (int j = 0; j < 15; j++) acc[j] = sb1[j];
        for (int k = 0; k < 10; k++) {
            float f = hv[k];
#pragma unroll
            for (int j = 0; j < 15; j++) acc[j] += f * sw1[k * 15 + j];
        }
        for (int k = 0; k < 15; k++) {
            float f = xv[k];
#pragma unroll
            for (int j = 0; j < 15; j++) acc[j] += f * sw1[(10 + k) * 15 + j];
        }
        for (int k = 0; k < 4; k++) {
            float f = sx2[k];
#pragma unroll
            for (int j = 0; j < 15; j++) acc[j] += f * sw1[(25 + k) * 15 + j];
        }
        vout = sb2v;
#pragma unroll
        for (int j = 0; j < 15; j++) { float r = (acc[j] > 0.f) ? acc[j] : 0.f; vout += r * sw2v[j]; }
    }
    red[threadIdx.x] = vout;
    __syncthreads();
    for (int s = 128; s > 0; s >>= 1) {
        if (threadIdx.x < (unsigned)s) red[threadIdx.x] += red[threadIdx.x + s];
        __syncthreads();
    }
    if (threadIdx.x == 0) atomicAdd(&g_vsum[0], red[0]);
}

// ---- attack scoring ----
__global__ void k_score_a(const int* __restrict__ asrc, const int* __restrict__ adst,
                          const float* __restrict__ aarm, const int* __restrict__ amove,
                          const float* __restrict__ aw, const float* __restrict__ ab,
                          const float* __restrict__ bw, const float* __restrict__ bb,
                          int Ma) {
    __shared__ float swa[20], sbias[20], sw2[20], sb2;
    float* pp = g_pp[blockIdx.x & (NPART - 1)];
    if (threadIdx.x < 20) {
        swa[threadIdx.x] = aw[46 * 20 + threadIdx.x] + 0.6f * aw[47 * 20 + threadIdx.x];
        sbias[threadIdx.x] = ab[threadIdx.x];
        sw2[threadIdx.x] = bw[threadIdx.x];
    }
    if (threadIdx.x == 0) sb2 = bb[0];
    __syncthreads();
    int i = blockIdx.x * blockDim.x + threadIdx.x;
    if (i >= Ma) return;
    int s = asrc[i], d = adst[i];
    float a = aarm[i];
    float us[20], ud[20];
    load_row20_bf(&g_us[(size_t)s * USU], us);
    load_row20_bf(&g_ud[(size_t)d * USU], ud);
    float sres = sb2;
#pragma unroll
    for (int j = 0; j < 20; j++) {
        float acc = sbias[j] + us[j] + ud[j] + a * swa[j];
        float r = (acc > 0.f) ? acc : 0.f;
        sres += r * sw2[j];
    }
    atomicAdd(&pp[amove[i]], sres);
}

// ---- deploy scoring ----
__global__ void k_score_d(const int* __restrict__ dtar, const float* __restrict__ darm,
                          const int* __restrict__ dmove,
                          const float* __restrict__ cw, const float* __restrict__ cb,
                          const float* __restrict__ dw, const float* __restrict__ db,
                          int Md) {
    __shared__ float swa[20], sbias[20], sw2[20], sb2;
    float* pp = g_pp[blockIdx.x & (NPART - 1)];
    if (threadIdx.x < 20) {
        swa[threadIdx.x] = cw[22 * 20 + threadIdx.x];
        sbias[threadIdx.x] = cb[threadIdx.x];
        sw2[threadIdx.x] = dw[threadIdx.x];
    }
    if (threadIdx.x == 0) sb2 = db[0];
    __syncthreads();
    int i = blockIdx.x * blockDim.x + threadIdx.x;
    if (i >= Md) return;
    int t = dtar[i];
    float a = darm[i];
    float ut[20];
    load_row20_bf(&g_ut[(size_t)t * USU], ut);
    float sres = sb2;
#pragma unroll
    for (int j = 0; j < 20; j++) {
        float acc = sbias[j] + ut[j] + a * swa[j];
        float r = (acc > 0.f) ? acc : 0.f;
        sres += r * sw2[j];
    }
    atomicAdd(&pp[dmove[i]], sres);
}

// -------- finalize (parallel) --------
__global__ void k_reduce(int M) {
    __shared__ float red[256];
    int i = blockIdx.x * 256 + threadIdx.x;
    float s = -1e30f;
    if (i < M) {
        float t = 0.f;
#pragma unroll
        for (int q = 0; q < NPART; q++) t += g_pp[q][i];
        g_p[i] = t;
        s = t;
    }
    red[threadIdx.x] = s;
    __syncthreads();
    for (int d = 128; d > 0; d >>= 1) {
        if (threadIdx.x < d) red[threadIdx.x] = fmaxf(red[threadIdx.x], red[threadIdx.x + d]);
        __syncthreads();
    }
    float bmax = red[0];
    __syncthreads();
    red[threadIdx.x] = (i < M) ? __expf(s - bmax) : 0.f;
    __syncthreads();
    for (int d = 128; d > 0; d >>= 1) {
        if (threadIdx.x < d) red[threadIdx.x] += red[threadIdx.x + d];
        __syncthreads();
    }
    if (threadIdx.x == 0) { g_bmax[blockIdx.x] = bmax; g_bsum[blockIdx.x] = red[0]; }
}

__global__ void k_lse(float* __restrict__ out, int N, int nrb) {
    __shared__ float rm[256], rs[256];
    int tid = threadIdx.x;
    float mx = -1e30f;
    for (int i = tid; i < nrb; i += 256) mx = fmaxf(mx, g_bmax[i]);
    rm[tid] = mx;
    __syncthreads();
    for (int d = 128; d > 0; d >>= 1) {
        if (tid < d) rm[tid] = fmaxf(rm[tid], rm[tid + d]);
        __syncthreads();
    }
    float pmax = rm[0];
    __syncthreads();
    float sm = 0.f;
    for (int i = tid; i < nrb; i += 256) sm += g_bsum[i] * __expf(g_bmax[i] - pmax);
    rs[tid] = sm;
    __syncthreads();
    for (int d = 128; d > 0; d >>= 1) {
        if (tid < d) rs[tid] += rs[tid + d];
        __syncthreads();
    }
    if (tid == 0) {
        g_lse[0] = pmax + logf(rs[0]);
        out[0] = tanhf(g_vsum[0] / (float)N);
    }
}

__global__ void k_write(float* __restrict__ out, int M) {
    int i = blockIdx.x * 256 + threadIdx.x;
    if (i < M) out[1 + i] = g_p[i] - g_lse[0];
}

extern "C" void kernel_launch(void* const* d_in, const int* in_sizes, int n_in,
                              void* d_out, int out_size, void* d_ws, size_t ws_size,
                              hipStream_t stream) {
    const float* x1 = (const float*)d_in[0];
    const float* x2 = (const float*)d_in[1];
    const int* edges = (const int*)d_in[2];
    const int* asrc = (const int*)d_in[3];
    const int* adst = (const int*)d_in[4];
    const float* aarm = (const float*)d_in[5];
    const int* amove = (const int*)d_in[6];
    const int* dtar = (const int*)d_in[7];
    const float* darm = (const float*)d_in[8];
    const int* dmove = (const int*)d_in[9];
    const int pb = n_in - 24;
    const float* g1_wl  = (const float*)d_in[pb + 0];
    const float* g1_wr  = (const float*)d_in[pb + 1];
    const float* g1_att = (const float*)d_in[pb + 2];
    const float* g1_b   = (const float*)d_in[pb + 3];
    const float* g2_wl  = (const float*)d_in[pb + 4];
    const float* g2_wr  = (const float*)d_in[pb + 5];
    const float* g2_att = (const float*)d_in[pb + 6];
    const float* g2_b   = (const float*)d_in[pb + 7];
    const float* g3_wl  = (const float*)d_in[pb + 8];
    const float* g3_wr  = (const float*)d_in[pb + 9];
    const float* g3_att = (const float*)d_in[pb + 10];
    const float* g3_b   = (const float*)d_in[pb + 11];
    const float* lin_w  = (const float*)d_in[pb + 12];
    const float* lin_b  = (const float*)d_in[pb + 13];
    const float* lin2_w = (const float*)d_in[pb + 14];
    const float* lin2_b = (const float*)d_in[pb + 15];
    const float* aaa_w  = (const float*)d_in[pb + 16];
    const float* aaa_b  = (const float*)d_in[pb + 17];
    const float* bbb_w  = (const float*)d_in[pb + 18];
    const float* bbb_b  = (const float*)d_in[pb + 19];
    const float* ccc_w  = (const float*)d_in[pb + 20];
    const float* ccc_b  = (const float*)d_in[pb + 21];
    const float* ddd_w  = (const float*)d_in[pb + 22];
    const float* ddd_b  = (const float*)d_in[pb + 23];

    int N = in_sizes[0] / 15;
    int E = in_sizes[2] / 2;
    const int Ma = in_sizes[3];
    const int Md = in_sizes[7];
    int M = out_size - 1;
    if (N > N_CAP) N = N_CAP;
    if (E > E_CAP) E = E_CAP;
    if (M > M_CAP) M = M_CAP;
    const int* src = edges;
    const int* dst = edges + E;

    const int nb = (N + 255) / 256;
    const int nb4 = (4 * N + 255) / 256;
    const int nbk = (N + (1 << BKS) - 1) >> BKS;
    const int nsc = (E + CHUNK - 1) / CHUNK;
    const int na = (Ma + 255) / 256, nd = (Md + 255) / 256;
    const int nrb = (M + 255) / 256;

    // init + single-pass CSR build (reused by all 3 layers)
    k_init<<<(NPART * M + 256) / 256, 256, 0, stream>>>(M);
    k_bscatter<<<nsc, 256, 0, stream>>>(src, dst, E);
    k_bgroup<<<nbk, 512, 0, stream>>>(N, nbk);

    // GAT layers: pre1 -> A; gather1+pre2 -> B; gather2+pre3 -> A; gather3 -> h
    k_pre1<<<nb, 256, 0, stream>>>(x1, g1_wl, g1_wr, N);
    k_gather_pre<<<nb4, 256, 0, stream>>>(x1, g1_att, g1_b, g2_wl, g2_wr, 0, N);
    k_gather_pre<<<nb4, 256, 0, stream>>>(x1, g2_att, g2_b, g3_wl, g3_wr, 1, N);
    k_gather3<<<nb4, 256, 0, stream>>>(g3_att, g3_b, 0, N);

    // u-row projection + value head, attack/deploy scoring, finalize
    k_prep_value<<<nb, 256, 0, stream>>>(x1, aaa_w, ccc_w, x2, lin_w, lin_b, lin2_w, lin2_b, N);
    k_score_a<<<na, 256, 0, stream>>>(asrc, adst, aarm, amove, aaa_w, aaa_b, bbb_w, bbb_b, Ma);
    k_score_d<<<nd, 256, 0, stream>>>(dtar, darm, dmove, ccc_w, ccc_b, ddd_w, ddd_b, Md);
    k_reduce<<<nrb, 256, 0, stream>>>(M);
    k_lse<<<1, 256, 0, stream>>>((float*)d_out, N, nrb);
    k_write<<<nrb, 256, 0, stream>>>((float*)d_out, M);
}